// Round 2
// baseline (742.388 us; speedup 1.0000x reference)
//
#include <hip/hip_runtime.h>
#include <math.h>

#define B_SZ   16384
#define D_EMB  128
#define D_HID  1024
#define D_FEAT 4096

typedef float f4 __attribute__((ext_vector_type(4)));

// ---------------------------------------------------------------------------
// Kernel A: h[g][m] = relu(ctx_g @ W1_g + b1_g).  grid = 8 blocks (2 gates x 4),
// 256 threads, one h-value per thread, coalesced W1 reads.
// ---------------------------------------------------------------------------
__global__ __launch_bounds__(256) void h_kernel(
    const float* __restrict__ ctx1, const float* __restrict__ ctx2,
    const float* __restrict__ W1a,  const float* __restrict__ b1a,
    const float* __restrict__ W1b,  const float* __restrict__ b1b,
    float* __restrict__ h /* [2][D_HID] */)
{
    const int g   = blockIdx.x >> 2;
    const int blk = blockIdx.x & 3;
    const float* ctx = g ? ctx2 : ctx1;
    const float* W1  = g ? W1b  : W1a;
    const float* b1  = g ? b1b  : b1a;

    __shared__ float s_ctx[D_EMB];
    const int t = threadIdx.x;
    if (t < D_EMB) s_ctx[t] = ctx[t];
    __syncthreads();

    const int m = blk * 256 + t;
    float acc = b1[m];
#pragma unroll 8
    for (int i = 0; i < D_EMB; ++i)
        acc = fmaf(s_ctx[i], W1[i * D_HID + m], acc);
    h[g * D_HID + m] = acc > 0.0f ? acc : 0.0f;
}

// ---------------------------------------------------------------------------
// Kernel B: gates[g][j] = sigmoid(h_g @ W2_g[:,j] + b2_g[j]) * 2.
// grid = 256 blocks (2 gates x 128 blocks of 32 columns = 8 float4-cols).
// 256 threads = 8 f4-cols x 32 k-slices (32 k each). float4 W2 loads
// (4x fewer VMEM requests than scalar), LDS tree reduce over k-slices.
// ---------------------------------------------------------------------------
__global__ __launch_bounds__(256) void gate_kernel(
    const float* __restrict__ W2a, const float* __restrict__ b2a,
    const float* __restrict__ W2b, const float* __restrict__ b2b,
    const float* __restrict__ h,    /* [2][D_HID] */
    float* __restrict__ gates       /* [2][D_FEAT] */)
{
    const int g   = blockIdx.x >> 7;
    const int blk = blockIdx.x & 127;
    const f4*    W2 = (const f4*)(g ? W2b : W2a);
    const float* b2 = g ? b2b : b2a;

    __shared__ float s_h[D_HID];
    __shared__ f4 s_part[256];          // [tk][tj] = [32][8]

    const int t = threadIdx.x;
#pragma unroll
    for (int r = 0; r < D_HID / 256; ++r)
        s_h[t + 256 * r] = h[g * D_HID + t + 256 * r];
    __syncthreads();

    const int tj = t & 7;               // f4 column within the block's 8
    const int tk = t >> 3;              // k-slice 0..31 (32 k-terms each)
    const int j4 = blk * 8 + tj;        // global f4 column

    const f4* w = W2 + (size_t)(tk * 32) * (D_FEAT / 4) + j4;
    f4 p = {0.0f, 0.0f, 0.0f, 0.0f};
#pragma unroll 8
    for (int kk = 0; kk < 32; ++kk) {
        const float hv = s_h[tk * 32 + kk];
        const f4 wv = w[(size_t)kk * (D_FEAT / 4)];
        p.x = fmaf(hv, wv.x, p.x);
        p.y = fmaf(hv, wv.y, p.y);
        p.z = fmaf(hv, wv.z, p.z);
        p.w = fmaf(hv, wv.w, p.w);
    }
    s_part[t] = p;                      // index = tk*8 + tj
    __syncthreads();

    // Tree-reduce over tk (stride 8 preserves tj lane).
#pragma unroll
    for (int s = 128; s >= 8; s >>= 1) {
        if (t < s) {
            f4 a = s_part[t], b = s_part[t + s];
            a.x += b.x; a.y += b.y; a.z += b.z; a.w += b.w;
            s_part[t] = a;
        }
        __syncthreads();
    }

    if (t < 8) {
        const int j = (blk * 8 + t) * 4;
        f4 a = s_part[t];
        a.x += b2[j + 0]; a.y += b2[j + 1]; a.z += b2[j + 2]; a.w += b2[j + 3];
        f4 gv;
        gv.x = 2.0f / (1.0f + expf(-a.x));
        gv.y = 2.0f / (1.0f + expf(-a.y));
        gv.z = 2.0f / (1.0f + expf(-a.z));
        gv.w = 2.0f / (1.0f + expf(-a.w));
        ((f4*)gates)[g * (D_FEAT / 4) + blk * 8 + t] = gv;
    }
}

// ---------------------------------------------------------------------------
// Kernel C: out1 = emb * g1, out2 = emb * g2.
// Canonical flat grid-stride float4 copy pattern (the 6.29 TB/s m13 shape):
// idx = tid, step = totalThreads. step is an exact multiple of the row width
// (524288 = 512 rows), so each thread's column is FIXED -> gates live in
// registers across all 32 iterations. PLAIN loads/stores (NT removed: the
// nt flag was the prime suspect for the ~3 TB/s result in R1).
// ---------------------------------------------------------------------------
__global__ __launch_bounds__(256) void mul_kernel(
    const f4* __restrict__ emb,
    const f4* __restrict__ gates,   // [2][D_FEAT/4]
    f4* __restrict__ out1,
    f4* __restrict__ out2)
{
    const int tid = blockIdx.x * 256 + threadIdx.x;   // 0..524287
    const int c   = tid & (D_FEAT / 4 - 1);           // fixed f4 column

    const f4 g1 = gates[c];
    const f4 g2 = gates[D_FEAT / 4 + c];

    size_t idx = (size_t)tid;
    const size_t step = (size_t)2048 * 256;           // total threads

#pragma unroll 8
    for (int r = 0; r < B_SZ / 512; ++r, idx += step) {
        const f4 e = emb[idx];
        out1[idx] = e * g1;
        out2[idx] = e * g2;
    }
}

extern "C" void kernel_launch(void* const* d_in, const int* in_sizes, int n_in,
                              void* d_out, int out_size, void* d_ws, size_t ws_size,
                              hipStream_t stream)
{
    const float* flat_emb = (const float*)d_in[0];
    const float* ctx1     = (const float*)d_in[1];
    const float* ctx2     = (const float*)d_in[2];
    const float* W1a      = (const float*)d_in[3];
    const float* b1a      = (const float*)d_in[4];
    const float* W2a      = (const float*)d_in[5];
    const float* b2a      = (const float*)d_in[6];
    const float* W1b      = (const float*)d_in[7];
    const float* b1b      = (const float*)d_in[8];
    const float* W2b      = (const float*)d_in[9];
    const float* b2b      = (const float*)d_in[10];

    float* out1  = (float*)d_out;
    float* out2  = (float*)d_out + (size_t)B_SZ * D_FEAT;
    float* gates = (float*)d_ws;                 // [2][D_FEAT] = 32 KB
    float* h     = (float*)d_ws + 2 * D_FEAT;    // [2][D_HID]  =  8 KB

    h_kernel<<<8, 256, 0, stream>>>(ctx1, ctx2, W1a, b1a, W1b, b1b, h);

    gate_kernel<<<256, 256, 0, stream>>>(W2a, b2a, W2b, b2b, h, gates);

    mul_kernel<<<2048, 256, 0, stream>>>(
        (const f4*)flat_emb, (const f4*)gates, (f4*)out1, (f4*)out2);
}